// Round 5
// baseline (426.679 us; speedup 1.0000x reference)
//
#include <hip/hip_runtime.h>

#define NTHREADS 256
#define KDIM 5

// out[n,g] = act( sum_{m,k,f} Ld[n,m,k]*v[m,f]*P[f,g,k] + Lu[n,m,k]*v[m,f]*Q[f,g,k] )
//
// Pure-streaming version: no LDS staging, no barriers. Block n owns output
// row n; each lane owns ONE m-row per iteration (5 floats, 20 B), so a wave's
// loads cover one contiguous 1280 B slab per stack. All 5 dword requests to a
// cache line issue back-to-back (MSHR-merged); latency is hidden by TLP
// (8 blocks/CU = 32 waves/CU).
template <int FIN, int FOUT, bool ACT>
__global__ __launch_bounds__(NTHREADS, 8)
void sc_pass(const float* __restrict__ Ld, const float* __restrict__ Lu,
             const float* __restrict__ v,   // [N, FIN]  (48 KB max: L2-resident)
             const float* __restrict__ P,   // [FIN, FOUT, K]
             const float* __restrict__ Q,   // [FIN, FOUT, K]
             float* __restrict__ out)       // [N, FOUT]
{
    constexpr int N = 4096;
    constexpr int NA = KDIM * FIN;
    constexpr int NITER = N / NTHREADS;     // 16

    const int n    = blockIdx.x;
    const int tid  = threadIdx.x;
    const int wid  = tid >> 6;
    const int lane = tid & 63;

    const float* __restrict__ ldrow = Ld + (size_t)n * N * KDIM;
    const float* __restrict__ lurow = Lu + (size_t)n * N * KDIM;

    float accd[NA], accu[NA];
#pragma unroll
    for (int j = 0; j < NA; ++j) { accd[j] = 0.f; accu[j] = 0.f; }

    for (int i = 0; i < NITER; ++i) {
        const int m = i * NTHREADS + tid;          // lanes contiguous in m
        const float* __restrict__ pd = ldrow + (size_t)m * KDIM;
        const float* __restrict__ pu = lurow + (size_t)m * KDIM;

        float ldv[KDIM], luv[KDIM], sv[FIN];
#pragma unroll
        for (int q = 0; q < KDIM; ++q) ldv[q] = pd[q];
#pragma unroll
        for (int q = 0; q < KDIM; ++q) luv[q] = pu[q];
#pragma unroll
        for (int f = 0; f < FIN; ++f) sv[f] = v[(size_t)m * FIN + f];

#pragma unroll
        for (int k = 0; k < KDIM; ++k)
#pragma unroll
            for (int f = 0; f < FIN; ++f) {
                accd[k * FIN + f] += ldv[k] * sv[f];
                accu[k * FIN + f] += luv[k] * sv[f];
            }
    }

    // ---- block reduction: 2*NA scalars ----
    __shared__ float red[NTHREADS / 64][2 * NA];
#pragma unroll
    for (int j = 0; j < NA; ++j) {
        float vd = accd[j], vu = accu[j];
#pragma unroll
        for (int off = 32; off > 0; off >>= 1) {
            vd += __shfl_xor(vd, off);
            vu += __shfl_xor(vu, off);
        }
        if (lane == 0) { red[wid][j] = vd; red[wid][NA + j] = vu; }
    }
    __syncthreads();

    if (tid == 0) {
        float h[FOUT];
#pragma unroll
        for (int g = 0; g < FOUT; ++g) h[g] = 0.f;
#pragma unroll
        for (int k = 0; k < KDIM; ++k)
#pragma unroll
            for (int f = 0; f < FIN; ++f) {
                float td = 0.f, tu = 0.f;
#pragma unroll
                for (int w = 0; w < NTHREADS / 64; ++w) {
                    td += red[w][k * FIN + f];
                    tu += red[w][NA + k * FIN + f];
                }
#pragma unroll
                for (int g = 0; g < FOUT; ++g) {
                    h[g] += td * P[(f * FOUT + g) * KDIM + k]
                          + tu * Q[(f * FOUT + g) * KDIM + k];
                }
            }
#pragma unroll
        for (int g = 0; g < FOUT; ++g) {
            float hv = h[g];
            out[(size_t)n * FOUT + g] = ACT ? (hv >= 0.f ? hv : 0.01f * hv) : hv;
        }
    }
}

extern "C" void kernel_launch(void* const* d_in, const int* in_sizes, int n_in,
                              void* d_out, int out_size, void* d_ws, size_t ws_size,
                              hipStream_t stream) {
    constexpr int N = 4096;
    const float* Ld = (const float*)d_in[0];
    const float* Lu = (const float*)d_in[1];
    const float* x  = (const float*)d_in[2];
    const float* P1 = (const float*)d_in[3];
    const float* Q1 = (const float*)d_in[4];
    const float* P2 = (const float*)d_in[5];
    const float* Q2 = (const float*)d_in[6];
    const float* P3 = (const float*)d_in[7];
    const float* Q3 = (const float*)d_in[8];
    float* out = (float*)d_out;

    float* s1 = (float*)d_ws;          // sigma(h1): [N,3]
    float* s2 = s1 + (size_t)N * 3;    // sigma(h2): [N,3]

    sc_pass<1, 3, true ><<<N, NTHREADS, 0, stream>>>(Ld, Lu, x,  P1, Q1, s1);
    sc_pass<3, 3, true ><<<N, NTHREADS, 0, stream>>>(Ld, Lu, s1, P2, Q2, s2);
    sc_pass<3, 1, false><<<N, NTHREADS, 0, stream>>>(Ld, Lu, s2, P3, Q3, out);
}

// Round 6
// 348.191 us; speedup vs baseline: 1.2254x; 1.2254x over previous
//
#include <hip/hip_runtime.h>

#define NTHREADS 256
#define KDIM 5
#define CHUNK_M 256
#define CHUNK_FLOATS (CHUNK_M * KDIM)   // 1280 floats = 5 KB per stack
#define NCHUNK (4096 / CHUNK_M)         // 16
#define NBUF 2                          // depth-1 prefetch + current (R2-proven scheme)

#define WAITV(n) asm volatile("s_waitcnt vmcnt(" #n ")" ::: "memory")

typedef float __attribute__((address_space(3))) lds_f;
typedef const float __attribute__((address_space(1))) glb_f;

// out[n,g] = act( sum_{m,k,f} Ld[n,m,k]*v[m,f]*P[f,g,k] + Lu[n,m,k]*v[m,f]*Q[f,g,k] )
// Block handles one output row. Stacks + v stream through a 2-buffer LDS
// pipeline via global_load_lds (widths 16/4 only); counted vmcnt (never
// drained mid-loop), 2 barriers/chunk. 26.6 KB LDS -> 6 blocks/CU = 24 waves.
// REV flips row order per pass (boustrophedon) for cross-pass L3 reuse.
template <int FIN, int FOUT, bool ACT, bool REV>
__global__ __launch_bounds__(NTHREADS)
void sc_pass(const float* __restrict__ Ld, const float* __restrict__ Lu,
             const float* __restrict__ v,   // [N, FIN]
             const float* __restrict__ P,   // [FIN, FOUT, K]
             const float* __restrict__ Q,   // [FIN, FOUT, K]
             float* __restrict__ out)       // [N, FOUT]
{
    constexpr int N = 4096;
    constexpr int NA = KDIM * FIN;
    constexpr int VCHUNK = CHUNK_M * FIN;

    __shared__ float sLd[NBUF][CHUNK_FLOATS];   // 10 KB
    __shared__ float sLu[NBUF][CHUNK_FLOATS];   // 10 KB
    __shared__ float sV [NBUF][VCHUNK];         // 6 KB (FIN=3) / 2 KB (FIN=1)
    __shared__ float red[NTHREADS / 64][2 * NA];

    const int n    = REV ? (N - 1 - blockIdx.x) : blockIdx.x;
    const int tid  = threadIdx.x;
    const int wid  = tid >> 6;
    const int lane = tid & 63;

    const float* __restrict__ ldrow = Ld + (size_t)n * N * KDIM;
    const float* __restrict__ lurow = Lu + (size_t)n * N * KDIM;

    // Stage chunk c into buffer b: (4 + FIN) global_load_lds per wave.
    // Stacks: wave wid owns floats [wid*320 .. wid*320+319] of the 1280-float
    // chunk: one width-16 (lane*16B) + one width-4 (lane*4B).
    // v: wave wid owns FIN width-4 loads of 64 floats each.
    auto stage = [&](int c, int b) {
        const size_t cbase = (size_t)c * CHUNK_FLOATS;
        const int wf = wid * 320;
        __builtin_amdgcn_global_load_lds((glb_f*)(ldrow + cbase + wf + lane * 4),
                                         (lds_f*)&sLd[b][wf], 16, 0, 0);
        __builtin_amdgcn_global_load_lds((glb_f*)(ldrow + cbase + wf + 256 + lane),
                                         (lds_f*)&sLd[b][wf + 256], 4, 0, 0);
        __builtin_amdgcn_global_load_lds((glb_f*)(lurow + cbase + wf + lane * 4),
                                         (lds_f*)&sLu[b][wf], 16, 0, 0);
        __builtin_amdgcn_global_load_lds((glb_f*)(lurow + cbase + wf + 256 + lane),
                                         (lds_f*)&sLu[b][wf + 256], 4, 0, 0);
        const int vf = wid * 64 * FIN;
#pragma unroll
        for (int j = 0; j < FIN; ++j) {
            __builtin_amdgcn_global_load_lds(
                (glb_f*)(v + (size_t)c * VCHUNK + vf + j * 64 + lane),
                (lds_f*)&sV[b][vf + j * 64], 4, 0, 0);
        }
    };

    float accd[NA], accu[NA];
#pragma unroll
    for (int j = 0; j < NA; ++j) { accd[j] = 0.f; accu[j] = 0.f; }

    stage(0, 0);
    stage(1, 1);   // 2*(4+FIN) loads outstanding per wave

    for (int c = 0; c < NCHUNK; ++c) {
        // Wait for chunk c's (4+FIN) loads; keep chunk c+1's in flight.
        if constexpr (FIN == 3) {
            if (c + 1 < NCHUNK) WAITV(7); else WAITV(0);
        } else {
            if (c + 1 < NCHUNK) WAITV(5); else WAITV(0);
        }
        __builtin_amdgcn_s_barrier();    // all waves' chunk-c data in LDS

        const int b = c & 1;

        float sv[FIN];
#pragma unroll
        for (int f = 0; f < FIN; ++f) sv[f] = sV[b][tid * FIN + f];

        // stride 5 (and 3) coprime with 32 banks -> 2 lanes/bank -> free.
        float ldv[KDIM], luv[KDIM];
#pragma unroll
        for (int q = 0; q < KDIM; ++q) {
            ldv[q] = sLd[b][tid * KDIM + q];
            luv[q] = sLu[b][tid * KDIM + q];
        }
#pragma unroll
        for (int k = 0; k < KDIM; ++k)
#pragma unroll
            for (int f = 0; f < FIN; ++f) {
                accd[k * FIN + f] += ldv[k] * sv[f];
                accu[k * FIN + f] += luv[k] * sv[f];
            }

        asm volatile("" ::: "memory");   // pin this chunk's LDS reads
        __builtin_amdgcn_s_barrier();    // all waves done reading buf b
        if (c + 2 < NCHUNK) stage(c + 2, b);   // overwrite buf just read: safe
    }

    // ---- block reduction: 2*NA scalars ----
#pragma unroll
    for (int j = 0; j < NA; ++j) {
        float vd = accd[j], vu = accu[j];
#pragma unroll
        for (int off = 32; off > 0; off >>= 1) {
            vd += __shfl_xor(vd, off);
            vu += __shfl_xor(vu, off);
        }
        if (lane == 0) { red[wid][j] = vd; red[wid][NA + j] = vu; }
    }
    __syncthreads();

    if (tid == 0) {
        float h[FOUT];
#pragma unroll
        for (int g = 0; g < FOUT; ++g) h[g] = 0.f;
#pragma unroll
        for (int k = 0; k < KDIM; ++k)
#pragma unroll
            for (int f = 0; f < FIN; ++f) {
                float td = 0.f, tu = 0.f;
#pragma unroll
                for (int w = 0; w < NTHREADS / 64; ++w) {
                    td += red[w][k * FIN + f];
                    tu += red[w][NA + k * FIN + f];
                }
#pragma unroll
                for (int g = 0; g < FOUT; ++g) {
                    h[g] += td * P[(f * FOUT + g) * KDIM + k]
                          + tu * Q[(f * FOUT + g) * KDIM + k];
                }
            }
#pragma unroll
        for (int g = 0; g < FOUT; ++g) {
            float hv = h[g];
            out[(size_t)n * FOUT + g] = ACT ? (hv >= 0.f ? hv : 0.01f * hv) : hv;
        }
    }
}

extern "C" void kernel_launch(void* const* d_in, const int* in_sizes, int n_in,
                              void* d_out, int out_size, void* d_ws, size_t ws_size,
                              hipStream_t stream) {
    constexpr int N = 4096;
    const float* Ld = (const float*)d_in[0];
    const float* Lu = (const float*)d_in[1];
    const float* x  = (const float*)d_in[2];
    const float* P1 = (const float*)d_in[3];
    const float* Q1 = (const float*)d_in[4];
    const float* P2 = (const float*)d_in[5];
    const float* Q2 = (const float*)d_in[6];
    const float* P3 = (const float*)d_in[7];
    const float* Q3 = (const float*)d_in[8];
    float* out = (float*)d_out;

    float* s1 = (float*)d_ws;          // sigma(h1): [N,3]
    float* s2 = s1 + (size_t)N * 3;    // sigma(h2): [N,3]

    // Boustrophedon: pass 2 reversed so it starts on rows pass 1 just
    // finished (L3-hot); pass 3 forward for the same reason vs pass 2.
    sc_pass<1, 3, true , false><<<N, NTHREADS, 0, stream>>>(Ld, Lu, x,  P1, Q1, s1);
    sc_pass<3, 3, true , true ><<<N, NTHREADS, 0, stream>>>(Ld, Lu, s1, P2, Q2, s2);
    sc_pass<3, 1, false, false><<<N, NTHREADS, 0, stream>>>(Ld, Lu, s2, P3, Q3, out);
}